// Round 15
// baseline (252.580 us; speedup 1.0000x reference)
//
#include <hip/hip_runtime.h>
#include <cstdint>
#include <cstddef>

#define DI __device__ __forceinline__

typedef int v4i  __attribute__((ext_vector_type(4)));
typedef int v16i __attribute__((ext_vector_type(16)));

#if defined(__has_builtin)
#if __has_builtin(__builtin_amdgcn_sdot4)
#define HAS_SDOT4 1
#endif
#if __has_builtin(__builtin_amdgcn_alignbyte)
#define HAS_ALIGNBYTE 1
#endif
#if __has_builtin(__builtin_amdgcn_global_load_lds)
#define HAS_GLLDS 1
#endif
#if __has_builtin(__builtin_amdgcn_perm)
#define HAS_PERM 1
#endif
#endif

DI unsigned alignb(unsigned hi, unsigned lo, int sh) {  // bytes (hi:lo) >> 8*sh
#ifdef HAS_ALIGNBYTE
  return __builtin_amdgcn_alignbyte(hi, lo, sh);
#else
  return sh ? ((lo >> (8 * sh)) | (hi << (32 - 8 * sh))) : lo;
#endif
}

// byte permute over (hi:lo); sel byte v in 0..3 -> lo.byte[v], 4..7 -> hi.byte[v-4]
DI unsigned bperm(unsigned hi, unsigned lo, unsigned sel) {
#ifdef HAS_PERM
  return __builtin_amdgcn_perm(hi, lo, sel);
#else
  unsigned r = 0;
#pragma unroll
  for (int i = 0; i < 4; ++i) {
    unsigned s = (sel >> (8 * i)) & 255u;
    unsigned b = (s < 4) ? (lo >> (8 * s)) : (hi >> (8 * (s - 4)));
    r |= (b & 255u) << (8 * i);
  }
  return r;
#endif
}

DI float qclamp(int a, float h) {  // clamp(rint(a*h), 0, 15) as float
  return fminf(fmaxf(rintf((float)a * h), 0.f), 15.f);
}

// quantize 3 consecutive floats -> 3 int8 codes in one dword (byte 3 = 0)
DI unsigned q3(const float* px, float s) {
  unsigned w = 0;
#pragma unroll
  for (int k = 0; k < 3; ++k) {
    float q = rintf(px[k] / s);
    q = fminf(fmaxf(q, -8.f), 7.f);
    w |= ((unsigned)((int)q & 255)) << (8 * k);
  }
  return w;
}

// ---------------- scalar block in workspace ----------------
struct Scal {
  unsigned max_x, max_w1, max_w2, max_wf1, max_wf2;  // float bits (abs-max, >=0)
  int max1, max2;
};

DI float mkscale(unsigned bits, float d) { return fmaxf(__uint_as_float(bits), 1e-8f) / d; }
DI float d_s_in(const Scal* sc) { return mkscale(sc->max_x, 7.f); }
DI float d_sw1(const Scal* sc)  { return mkscale(sc->max_w1, 7.f); }
DI float d_sw2(const Scal* sc)  { return mkscale(sc->max_w2, 7.f); }
DI float d_s1(const Scal* sc)   { return fmaxf((float)sc->max1 * (d_s_in(sc) * d_sw1(sc)), 1e-8f) / 15.f; }
DI float d_s2(const Scal* sc)   { return fmaxf((float)sc->max2 * (d_s1(sc) * d_sw2(sc)), 1e-8f) / 15.f; }

static constexpr int NX   = 32 * 3 * 224 * 224;     // 4,816,896
static constexpr int NP1  = 32 * 32 * 222 * 224;    // y1n bytes (planar rows)
static constexpr int C2_ROWB   = 224 * 32;          // 7168 B per y1n row
static constexpr int C2_HPLANE = 224 * 16;          // 3584 B per ic-half plane
static constexpr int C2V_BLK   = 1120;              // 8 XCD * 140 blocks
static constexpr int C2V_ROWS  = 22;                // out rows per wave (10 vslices)
static constexpr int C1V_BLK   = 2072;              // 8 XCD * 259; 8288 waves = 32*7*37
static constexpr int C1V_ROWS  = 6;                 // out rows per wave (37 vslices)

// ---------------- reduction helpers (up to 8 waves) ----------------
DI float wave_maxf(float v) { for (int o = 32; o; o >>= 1) v = fmaxf(v, __shfl_down(v, o, 64)); return v; }
DI int   wave_maxi(int v)   { for (int o = 32; o; o >>= 1) v = max(v, __shfl_down(v, o, 64));   return v; }

// NOTE: callers pass values >= 0; unused wave slots read as 0.
DI float block_maxf(float v) {
  __shared__ float s[8];
  v = wave_maxf(v);
  int lane = threadIdx.x & 63, w = threadIdx.x >> 6;
  int nw = (int)(blockDim.x >> 6);
  if (!lane) s[w] = v;
  __syncthreads();
  if (threadIdx.x < 64) {
    float t = ((int)threadIdx.x < nw) ? s[threadIdx.x] : 0.f;
    v = wave_maxf(t);
  }
  return v;
}

DI int block_maxi(int v) {
  __shared__ int s[8];
  v = wave_maxi(v);
  int lane = threadIdx.x & 63, w = threadIdx.x >> 6;
  int nw = (int)(blockDim.x >> 6);
  if (!lane) s[w] = v;
  __syncthreads();
  if (threadIdx.x < 64) {
    int t = ((int)threadIdx.x < nw) ? s[threadIdx.x] : 0;
    v = wave_maxi(t);
  }
  return v;
}

// ---------------- stage kernels ----------------
// merged absmax: blocks 0..1023 = x (grid-stride); 1024..1027 = weights
__global__ void k_absmax_xw(const float4* __restrict__ x, int n4,
                            const float* __restrict__ w1, const float* __restrict__ w2,
                            const float* __restrict__ wf1, const float* __restrict__ wf2,
                            Scal* sc) {
  if (blockIdx.x < 1024) {
    float m = 0.f;
    for (int i = blockIdx.x * 256 + threadIdx.x; i < n4; i += 1024 * 256) {
      float4 v = x[i];
      m = fmaxf(m, fmaxf(fmaxf(fabsf(v.x), fabsf(v.y)), fmaxf(fabsf(v.z), fabsf(v.w))));
    }
    m = block_maxf(m);
    if (!threadIdx.x) atomicMax(&sc->max_x, __float_as_uint(m));
    return;
  }
  const float* p; int n; unsigned* slot;
  int wb = blockIdx.x - 1024;
  if (wb == 0)      { p = w1;  n = 864;   slot = &sc->max_w1; }
  else if (wb == 1) { p = w2;  n = 18432; slot = &sc->max_w2; }
  else if (wb == 2) { p = wf1; n = 8192;  slot = &sc->max_wf1; }
  else              { p = wf2; n = 1280;  slot = &sc->max_wf2; }
  float m = 0.f;
  for (int i = threadIdx.x; i < n; i += 256) m = fmaxf(m, fabsf(p[i]));
  m = block_maxf(m);
  if (!threadIdx.x) atomicMax(slot, __float_as_uint(m));
}

// ---------------- conv1 via MFMA: vertical-strip waves, near-zero-LDS -----
// K-order: k = ic*9 + kh*3 + kw (27 taps, 5 zero-pad). A = w1 (32 oc rows),
// B = im2col codes (32 px cols), quantized IN REGISTERS from global x.
// Wave = (img, owg, vslice); walks 6 output rows. Codes held in a 4-bank
// rolling window cw[4][2] (2 ic-slots per K-half: lhalf0 -> ic0,ic1;
// lhalf1 -> ic1,ic2); one new input row (6 floats) loaded+quantized per
// iteration, prefetched one iter ahead. Weights/bias in 1.3KB LDS staged
// once (single barrier, none in loop). C layout: row oc=(r&3)+8*(r>>2)+
// 4*lhalf, col = pixel = lane&31 (validated).

// pack K-half 0 (k0..15) from tap words s0..s5 (3 valid bytes each)
DI void kpack0(const unsigned* R, v4i& f) {
  f[0] = (int)bperm(R[1], R[0], 0x04020100u);  // s0.b012, s1.b0
  f[1] = (int)bperm(R[2], R[1], 0x05040201u);  // s1.b12, s2.b01
  f[2] = (int)bperm(R[3], R[2], 0x06050402u);  // s2.b2, s3.b012
  f[3] = (int)bperm(R[5], R[4], 0x04020100u);  // s4.b012, s5.b0
}
// pack K-half 1 (k16..31) from tap words s5..s8
DI void kpack1(const unsigned* R, v4i& f) {
  f[0] = (int)bperm(R[1], R[0], 0x05040201u);  // s5.b12, s6.b01
  f[1] = (int)bperm(R[2], R[1], 0x06050402u);  // s6.b2, s7.b012
  f[2] = (int)bperm(0u,   R[3], 0x04020100u);  // s8.b012, 0
  f[3] = 0;                                     // pad k28..31
}

DI v4i conv1_afrag(const unsigned* lw, int oc, int lhalf) {
  unsigned R[6];
  v4i f;
  if (lhalf == 0) {
#pragma unroll
    for (int s = 0; s < 6; ++s) R[s] = lw[oc * 9 + s];
    kpack0(R, f);
  } else {
#pragma unroll
    for (int s = 0; s < 4; ++s) R[s] = lw[oc * 9 + 5 + s];
    kpack1(R, f);
  }
  return f;
}

// weight/bias staging for 256-thread blocks (single barrier by caller)
DI void conv1_wstage(const float* w1, const float* b1, int tid,
                     float s_in, float sw1, unsigned* lw, int* lb) {
  for (int i = tid; i < 288; i += 256) {
    int oc = i / 9, r = i - oc * 9;
    unsigned w = 0;
#pragma unroll
    for (int k = 0; k < 3; ++k) {
      float q = rintf(w1[oc * 27 + r * 3 + k] / sw1);
      q = fminf(fmaxf(q, -8.f), 7.f);
      w |= ((unsigned)((int)q & 255)) << (8 * k);
    }
    lw[i] = w;
  }
  if (tid < 32) lb[tid] = (int)rintf(b1[tid] / (s_in * sw1));
}

// build B-frag for output row t (relative): R[s] = cw[(t+kh)&3][slot]
#define C1_BFRAG(bf, t)                                                    \
  {                                                                        \
    unsigned R[6];                                                         \
    if (lhalf == 0) {                                                      \
      R[0] = cw[(t) & 3][0]; R[1] = cw[((t) + 1) & 3][0];                  \
      R[2] = cw[((t) + 2) & 3][0];                                         \
      R[3] = cw[(t) & 3][1]; R[4] = cw[((t) + 1) & 3][1];                  \
      R[5] = cw[((t) + 2) & 3][1];                                         \
      kpack0(R, bf);                                                       \
    } else {                                                               \
      R[0] = cw[((t) + 2) & 3][0];                                         \
      R[1] = cw[(t) & 3][1]; R[2] = cw[((t) + 1) & 3][1];                  \
      R[3] = cw[((t) + 2) & 3][1];                                         \
      kpack1(R, bf);                                                       \
    }                                                                      \
  }

// load+quantize one input row (relative row index rr, bank bk)
#define C1_LOAD(bk, rr)                                                    \
  {                                                                        \
    const float* r0 = xb + (size_t)(j0 + (rr)) * 224;                      \
    cw[bk][0] = q3(r0, s_in);                                              \
    cw[bk][1] = q3(r0 + 224 * 224, s_in);                                  \
  }

// pass A: MAX ONLY. Blocks >= C1V_BLK pack w2frag (MFMA B-frag layout).
__global__ void __launch_bounds__(256, 4) k_conv1a(
    const float* __restrict__ x, const float* __restrict__ w1,
    const float* __restrict__ b1, const float* __restrict__ w2,
    const Scal* __restrict__ sc, unsigned* __restrict__ w2frag,
    int* __restrict__ max1) {
  int tid = threadIdx.x;
  if (blockIdx.x >= C1V_BLK) {   // 18 blocks: pack w2 into MFMA B-frag layout
    int j = (blockIdx.x - C1V_BLK) * 256 + tid;   // 0..4607
    if (j < 4608) {
      int icq = j & 7; int t = j >> 3;
      int kw = t % 3; t /= 3;
      int kh = t % 3; int oc = t / 3;
      float s = d_sw2(sc);
      unsigned w = 0;
#pragma unroll
      for (int k = 0; k < 4; ++k) {
        int ic = icq * 4 + k;
        float q = rintf(w2[(oc * 32 + ic) * 9 + kh * 3 + kw] / s);
        q = fminf(fmaxf(q, -8.f), 7.f);
        w |= ((unsigned)((int)q & 255)) << (8 * k);
      }
      int tap = kh * 3 + kw;
      int dl = (oc & 31) | ((icq >> 2) << 5);
      w2frag[(((tap * 2) + (oc >> 5)) * 64 + dl) * 4 + (icq & 3)] = w;
    }
    return;
  }

  __shared__ unsigned lw[288];
  __shared__ int lb[32];
  float s_in = d_s_in(sc), sw1 = d_sw1(sc);
  conv1_wstage(w1, b1, tid, s_in, sw1, lw, lb);
  __syncthreads();

  int lane = tid & 63, wv = tid >> 6;
  int lane31 = lane & 31, lhalf = lane >> 5;
  int blk = (int)blockIdx.x;
  int blk2 = (blk & 7) * 259 + (blk >> 3);     // 2072 = 8*259, bijective
  int role = blk2 * 4 + wv;                    // img-major: 259 roles/img
  int img = role / 259;
  int rem = role - img * 259;
  int owg = rem % 7, vs = rem / 7;             // vs 0..36
  int j0 = vs * C1V_ROWS;
  int p = owg * 32 + lane31;
  int pc = (p < 222) ? p : 221;                // clamp loads for edge lanes

  v4i af = conv1_afrag(lw, lane31, lhalf);
  const v4i* lbv = (const v4i*)lb;
  v4i bq[4];
#pragma unroll
  for (int q = 0; q < 4; ++q) bq[q] = lbv[lhalf + 2 * q];

  int icA = lhalf ? 1 : 0;                     // slot0 plane
  const float* xb = x + ((size_t)(img * 3 + icA) * 224) * 224 + pc;

  unsigned cw[4][2];
  C1_LOAD(0, 0); C1_LOAD(1, 1); C1_LOAD(2, 2);

  int mx = 0;
#pragma unroll
  for (int t = 0; t < C1V_ROWS; ++t) {
    if (t < C1V_ROWS - 1) C1_LOAD((t + 3) & 3, t + 3);  // prefetch next row
    v4i bf;
    C1_BFRAG(bf, t);
    v16i acc;
#pragma unroll
    for (int q = 0; q < 4; ++q)
#pragma unroll
      for (int j = 0; j < 4; ++j) acc[4 * q + j] = bq[q][j];
    acc = __builtin_amdgcn_mfma_i32_32x32x32_i8(af, bf, acc, 0, 0, 0);
    if (p < 222) {
#pragma unroll
      for (int r = 0; r < 16; ++r) mx = max(mx, acc[r]);
    }
  }
  mx = block_maxi(max(mx, 0));
  if (!tid) atomicMax(max1, mx);
}

// pass B: recompute acc via MFMA, quantize, store planar codes
// row = [ichalf(2)][224 px][16 oc bytes].
__global__ void __launch_bounds__(256, 4) k_conv1b(
    const float* __restrict__ x, const float* __restrict__ w1,
    const float* __restrict__ b1, const Scal* __restrict__ sc,
    unsigned char* __restrict__ y1n) {
  __shared__ unsigned lw[288];
  __shared__ int lb[32];
  int tid = threadIdx.x;
  float s_in = d_s_in(sc), sw1 = d_sw1(sc);
  conv1_wstage(w1, b1, tid, s_in, sw1, lw, lb);
  __syncthreads();

  int lane = tid & 63, wv = tid >> 6;
  int lane31 = lane & 31, lhalf = lane >> 5;
  int blk = (int)blockIdx.x;
  int blk2 = (blk & 7) * 259 + (blk >> 3);
  int role = blk2 * 4 + wv;
  int img = role / 259;
  int rem = role - img * 259;
  int owg = rem % 7, vs = rem / 7;
  int j0 = vs * C1V_ROWS;
  int p = owg * 32 + lane31;
  int pc = (p < 222) ? p : 221;

  v4i af = conv1_afrag(lw, lane31, lhalf);
  const v4i* lbv = (const v4i*)lb;
  v4i bq[4];
#pragma unroll
  for (int q = 0; q < 4; ++q) bq[q] = lbv[lhalf + 2 * q];

  float h1 = (s_in * sw1) / d_s1(sc);
  int icA = lhalf ? 1 : 0;
  const float* xb = x + ((size_t)(img * 3 + icA) * 224) * 224 + pc;

  unsigned cw[4][2];
  C1_LOAD(0, 0); C1_LOAD(1, 1); C1_LOAD(2, 2);

#pragma unroll
  for (int t = 0; t < C1V_ROWS; ++t) {
    if (t < C1V_ROWS - 1) C1_LOAD((t + 3) & 3, t + 3);
    v4i bf;
    C1_BFRAG(bf, t);
    v16i acc;
#pragma unroll
    for (int q = 0; q < 4; ++q)
#pragma unroll
      for (int j = 0; j < 4; ++j) acc[4 * q + j] = bq[q][j];
    acc = __builtin_amdgcn_mfma_i32_32x32x32_i8(af, bf, acc, 0, 0, 0);
    if (p < 222) {
      size_t rowb = (size_t)(img * 222 + j0 + t) * C2_ROWB;
      unsigned char* dst0 = y1n + rowb + (size_t)p * 16;
#pragma unroll
      for (int q = 0; q < 4; ++q) {
        int oc0 = 8 * q + 4 * lhalf;       // C row = (r&3)+8*(r>>2)+4*lhalf
        unsigned cwd = 0;
#pragma unroll
        for (int j = 0; j < 4; ++j)
          cwd |= ((unsigned)(int)qclamp(acc[4 * q + j], h1)) << (8 * j);
        *(unsigned*)(dst0 + (oc0 >> 4) * C2_HPLANE + (oc0 & 15)) = cwd;
      }
    }
  }
}

// ---------------- conv2: vertical-strip waves + register rolling window ---
// Wave = (img, owg, oc-half, vslice); walks 22 consecutive output rows.
// 9 weight B-frags in registers; A held in a 4-bank register window A[4][3]
// — each iteration prefetches ONE new input row (3 dwordx4) into the free
// bank one full iteration before use. Scalar bias + per-row acc init.

__global__ void __launch_bounds__(256, 4) k_conv2a(
    const unsigned char* __restrict__ y1n, const unsigned* __restrict__ w2frag,
    const float* __restrict__ b2, const Scal* __restrict__ sc, int* __restrict__ max2) {
  int tid = threadIdx.x;
  int lane = tid & 63, wv = tid >> 6;
  int lane31 = lane & 31, lhalf = lane >> 5;
  int blk = (int)blockIdx.x;
  int blk2 = (blk & 7) * 140 + (blk >> 3);     // 1120 = 8*140, bijective
  int role = blk2 * 4 + wv;                    // img-major: 140 roles/img
  int img = role / 140;
  int rem = role - img * 140;
  int owg = rem % 7;
  int t7 = rem / 7;
  int hh = t7 & 1;
  int vs = t7 >> 1;
  int j0 = vs * C2V_ROWS;
  int ow0 = owg * 32;

  v4i wb[9];
  const v4i* gW = (const v4i*)w2frag;
#pragma unroll
  for (int t = 0; t < 9; ++t) wb[t] = gW[(t * 2 + hh) * 64 + lane];

  float sb = d_s1(sc) * d_sw2(sc);
  int bias = (int)rintf(b2[hh * 32 + lane31] / sb);

  const unsigned char* base = y1n + (size_t)(img * 222 + j0) * C2_ROWB
                              + (size_t)lhalf * C2_HPLANE
                              + (size_t)(ow0 + lane31) * 16;
  v4i A[4][3];
#pragma unroll
  for (int r = 0; r < 3; ++r)
#pragma unroll
    for (int kw = 0; kw < 3; ++kw)
      A[r][kw] = *(const v4i*)(base + (size_t)r * C2_ROWB + kw * 16);

  int mx = 0;
#pragma unroll
  for (int jj = 0; jj < C2V_ROWS; ++jj) {
    if (jj < C2V_ROWS - 1) {                   // prefetch row jj+3 (<= 23)
      const unsigned char* rp = base + (size_t)(jj + 3) * C2_ROWB;
#pragma unroll
      for (int kw = 0; kw < 3; ++kw)
        A[(jj + 3) & 3][kw] = *(const v4i*)(rp + kw * 16);
    }
    v16i acc;
#pragma unroll
    for (int r = 0; r < 16; ++r) acc[r] = bias;
#pragma unroll
    for (int kh = 0; kh < 3; ++kh)
#pragma unroll
      for (int kw = 0; kw < 3; ++kw)
        acc = __builtin_amdgcn_mfma_i32_32x32x32_i8(A[(jj + kh) & 3][kw], wb[kh * 3 + kw], acc, 0, 0, 0);

    if (owg != 6) {
#pragma unroll
      for (int r = 0; r < 16; ++r) mx = max(mx, acc[r]);
    } else {
#pragma unroll
      for (int r = 0; r < 16; ++r) {
        int m = (r & 3) + 8 * (r >> 2) + 4 * lhalf;
        if (ow0 + m < 220) mx = max(mx, acc[r]);
      }
    }
  }
  mx = block_maxi(max(mx, 0));
  if (!tid) atomicMax(max2, mx);
}

__global__ void __launch_bounds__(256, 4) k_conv2b(
    const unsigned char* __restrict__ y1n, const unsigned* __restrict__ w2frag,
    const float* __restrict__ b2, const Scal* __restrict__ sc,
    int* __restrict__ pooled_i) {
  int tid = threadIdx.x;
  int lane = tid & 63, wv = tid >> 6;
  int lane31 = lane & 31, lhalf = lane >> 5;
  int blk = (int)blockIdx.x;
  int blk2 = (blk & 7) * 140 + (blk >> 3);
  int role = blk2 * 4 + wv;
  int img = role / 140;
  int rem = role - img * 140;
  int owg = rem % 7;
  int t7 = rem / 7;
  int hh = t7 & 1;
  int vs = t7 >> 1;
  int j0 = vs * C2V_ROWS;
  int ow0 = owg * 32;

  v4i wb[9];
  const v4i* gW = (const v4i*)w2frag;
#pragma unroll
  for (int t = 0; t < 9; ++t) wb[t] = gW[(t * 2 + hh) * 64 + lane];

  float sb = d_s1(sc) * d_sw2(sc);
  int bias = (int)rintf(b2[hh * 32 + lane31] / sb);
  float h1 = sb * (1.0f / d_s2(sc));

  const unsigned char* base = y1n + (size_t)(img * 222 + j0) * C2_ROWB
                              + (size_t)lhalf * C2_HPLANE
                              + (size_t)(ow0 + lane31) * 16;
  v4i A[4][3];
#pragma unroll
  for (int r = 0; r < 3; ++r)
#pragma unroll
    for (int kw = 0; kw < 3; ++kw)
      A[r][kw] = *(const v4i*)(base + (size_t)r * C2_ROWB + kw * 16);

  float psum = 0.f;
#pragma unroll
  for (int jj = 0; jj < C2V_ROWS; ++jj) {
    if (jj < C2V_ROWS - 1) {                   // prefetch row jj+3 (<= 23)
      const unsigned char* rp = base + (size_t)(jj + 3) * C2_ROWB;
#pragma unroll
      for (int kw = 0; kw < 3; ++kw)
        A[(jj + 3) & 3][kw] = *(const v4i*)(rp + kw * 16);
    }
    v16i acc;
#pragma unroll
    for (int r = 0; r < 16; ++r) acc[r] = bias;
#pragma unroll
    for (int kh = 0; kh < 3; ++kh)
#pragma unroll
      for (int kw = 0; kw < 3; ++kw)
        acc = __builtin_amdgcn_mfma_i32_32x32x32_i8(A[(jj + kh) & 3][kw], wb[kh * 3 + kw], acc, 0, 0, 0);

    if (owg != 6) {
#pragma unroll
      for (int r = 0; r < 16; ++r) psum += qclamp(acc[r], h1);
    } else {
#pragma unroll
      for (int r = 0; r < 16; ++r) {
        int m = (r & 3) + 8 * (r >> 2) + 4 * lhalf;
        if (ow0 + m < 220) psum += qclamp(acc[r], h1);
      }
    }
  }
  int s = (int)psum;
  s += __shfl_down(s, 32, 64);                 // combine px-halves (same oc)
  if (lhalf == 0) atomicAdd(&pooled_i[img * 64 + hh * 32 + lane31], s);
}

// whole FC head + log_softmax in one 1024-thread block.
// wq1 stride 68 (f4-aligned); y3 stride 132.
__global__ void __launch_bounds__(1024) k_fc(
    const int* __restrict__ pooled_i, const float* __restrict__ wf1,
    const float* __restrict__ bf1, const float* __restrict__ wf2,
    const float* __restrict__ bf2, const Scal* __restrict__ sc,
    float* __restrict__ out) {
  __shared__ float pl[2048];
  __shared__ __align__(16) float wq1[128 * 68];
  __shared__ __align__(16) float y3[32 * 132];
  __shared__ float zz[320];
  __shared__ float s3sh;
  __shared__ float red16[16];
  int tid = threadIdx.x;
  float swf1 = mkscale(sc->max_wf1, 7.f), swf2 = mkscale(sc->max_wf2, 7.f);
  float s2 = d_s2(sc);
  for (int i = tid; i < 2048; i += 1024) pl[i] = (float)pooled_i[i] * s2 / 48400.0f;
  for (int i = tid; i < 8192; i += 1024) {
    float q = rintf(wf1[i] / swf1);
    q = fminf(fmaxf(q, -8.f), 7.f);
    wq1[(i >> 6) * 68 + (i & 63)] = q * swf1;
  }
  __syncthreads();
  float sb1 = s2 * swf1;
  float lmax = 0.f;
#pragma unroll
  for (int o = tid; o < 4096; o += 1024) {
    int b = o >> 7, j = o & 127;
    float acc = rintf(bf1[j] / sb1) * sb1;
    const float4* wr4 = (const float4*)&wq1[j * 68];
    const float4* xr4 = (const float4*)&pl[b * 64];
#pragma unroll
    for (int k4 = 0; k4 < 16; ++k4) {
      float4 w4 = wr4[k4], x4 = xr4[k4];
      acc += x4.x * w4.x + x4.y * w4.y + x4.z * w4.z + x4.w * w4.w;
    }
    float r = fmaxf(acc, 0.f);
    y3[b * 132 + j] = r;
    lmax = fmaxf(lmax, r);
  }
  lmax = wave_maxf(lmax);
  {
    int lane = tid & 63, w = tid >> 6;
    if (!lane) red16[w] = lmax;
  }
  __syncthreads();
  if (tid < 64) {
    float t = (tid < 16) ? red16[tid] : 0.f;
    t = wave_maxf(t);
    if (!tid) s3sh = fmaxf(t, 1e-8f) / 15.f;
  }
  __syncthreads();
  float s3 = s3sh;
  float sb2 = s3 * swf2;
  if (tid < 320) {
    int o = tid;
    int b = o / 10, j = o - b * 10;
    float acc = rintf(bf2[j] / sb2) * sb2;
    const float4* yy4 = (const float4*)&y3[b * 132];
    const float4* wr4 = (const float4*)&wf2[j * 128];
#pragma unroll 8
    for (int k4 = 0; k4 < 32; ++k4) {
      float4 y4 = yy4[k4];
      float4 w4 = wr4[k4];
      float yv[4] = {y4.x, y4.y, y4.z, y4.w};
      float wv4[4] = {w4.x, w4.y, w4.z, w4.w};
#pragma unroll
      for (int e = 0; e < 4; ++e) {
        float q = rintf(yv[e] / s3);
        q = fminf(fmaxf(q, 0.f), 15.f);
        float wv = rintf(wv4[e] / swf2);
        wv = fminf(fmaxf(wv, -8.f), 7.f);
        acc += (q * s3) * (wv * swf2);
      }
    }
    zz[o] = acc;
  }
  __syncthreads();
  if (tid < 32) {
    const float* z = &zz[tid * 10];
    float mm = z[0];
    for (int k = 1; k < 10; ++k) mm = fmaxf(mm, z[k]);
    float ssum = 0.f;
    for (int k = 0; k < 10; ++k) ssum += expf(z[k] - mm);
    float l = mm + logf(ssum);
    for (int k = 0; k < 10; ++k) out[tid * 10 + k] = z[k] - l;
  }
}

extern "C" void kernel_launch(void* const* d_in, const int* in_sizes, int n_in,
                              void* d_out, int out_size, void* d_ws, size_t ws_size,
                              hipStream_t stream) {
  const float* x   = (const float*)d_in[0];
  const float* w1  = (const float*)d_in[1];
  const float* b1  = (const float*)d_in[2];
  const float* w2  = (const float*)d_in[3];
  const float* b2  = (const float*)d_in[4];
  const float* wf1 = (const float*)d_in[5];
  const float* bf1 = (const float*)d_in[6];
  const float* wf2 = (const float*)d_in[7];
  const float* bf2 = (const float*)d_in[8];
  float* out = (float*)d_out;

  char* ws = (char*)d_ws;
  Scal* sc = (Scal*)ws;
  int* pooled_i = (int*)(ws + 1024);            // sc + pooled zeroed by ONE memset
  size_t off = 1024 + 8192;
  unsigned* w2frag = (unsigned*)(ws + off);     off += 4608 * 4;          // MFMA B-frag layout
  off = (off + 255) & ~(size_t)255;
  unsigned char* y1n = (unsigned char*)(ws + off); off += (size_t)NP1 + 256; // planar codes + slack
  (void)ws_size; (void)in_sizes; (void)n_in; (void)out_size;

  hipMemsetAsync(ws, 0, 1024 + 8192, stream);
  k_absmax_xw<<<1028, 256, 0, stream>>>((const float4*)x, NX / 4, w1, w2, wf1, wf2, sc);
  k_conv1a<<<C1V_BLK + 18, 256, 0, stream>>>(x, w1, b1, w2, sc, w2frag, &sc->max1);
  k_conv1b<<<C1V_BLK, 256, 0, stream>>>(x, w1, b1, sc, y1n);
  k_conv2a<<<C2V_BLK, 256, 0, stream>>>(y1n, w2frag, b2, sc, &sc->max2);
  k_conv2b<<<C2V_BLK, 256, 0, stream>>>(y1n, w2frag, b2, sc, pooled_i);
  k_fc<<<1, 1024, 0, stream>>>(pooled_i, wf1, bf1, wf2, bf2, sc, out);
}

// Round 16
// 242.046 us; speedup vs baseline: 1.0435x; 1.0435x over previous
//
#include <hip/hip_runtime.h>
#include <cstdint>
#include <cstddef>

#define DI __device__ __forceinline__

typedef int v4i  __attribute__((ext_vector_type(4)));
typedef int v16i __attribute__((ext_vector_type(16)));

#if defined(__has_builtin)
#if __has_builtin(__builtin_amdgcn_sdot4)
#define HAS_SDOT4 1
#endif
#if __has_builtin(__builtin_amdgcn_alignbyte)
#define HAS_ALIGNBYTE 1
#endif
#if __has_builtin(__builtin_amdgcn_global_load_lds)
#define HAS_GLLDS 1
#endif
#if __has_builtin(__builtin_amdgcn_perm)
#define HAS_PERM 1
#endif
#endif

DI unsigned alignb(unsigned hi, unsigned lo, int sh) {  // bytes (hi:lo) >> 8*sh
#ifdef HAS_ALIGNBYTE
  return __builtin_amdgcn_alignbyte(hi, lo, sh);
#else
  return sh ? ((lo >> (8 * sh)) | (hi << (32 - 8 * sh))) : lo;
#endif
}

// byte permute over (hi:lo); sel byte v in 0..3 -> lo.byte[v], 4..7 -> hi.byte[v-4]
DI unsigned bperm(unsigned hi, unsigned lo, unsigned sel) {
#ifdef HAS_PERM
  return __builtin_amdgcn_perm(hi, lo, sel);
#else
  unsigned r = 0;
#pragma unroll
  for (int i = 0; i < 4; ++i) {
    unsigned s = (sel >> (8 * i)) & 255u;
    unsigned b = (s < 4) ? (lo >> (8 * s)) : (hi >> (8 * (s - 4)));
    r |= (b & 255u) << (8 * i);
  }
  return r;
#endif
}

DI float qclamp(int a, float h) {  // clamp(rint(a*h), 0, 15) as float
  return fminf(fmaxf(rintf((float)a * h), 0.f), 15.f);
}

// quantize 3 consecutive floats -> 3 int8 codes in one dword (byte 3 = 0)
DI unsigned q3(const float* px, float s) {
  unsigned w = 0;
#pragma unroll
  for (int k = 0; k < 3; ++k) {
    float q = rintf(px[k] / s);
    q = fminf(fmaxf(q, -8.f), 7.f);
    w |= ((unsigned)((int)q & 255)) << (8 * k);
  }
  return w;
}

// ---------------- scalar block in workspace ----------------
struct Scal {
  unsigned max_x, max_w1, max_w2, max_wf1, max_wf2;  // float bits (abs-max, >=0)
  int max1, max2;
  unsigned max3;                                      // relu(fc1) max, float bits
};

DI float mkscale(unsigned bits, float d) { return fmaxf(__uint_as_float(bits), 1e-8f) / d; }
DI float d_s_in(const Scal* sc) { return mkscale(sc->max_x, 7.f); }
DI float d_sw1(const Scal* sc)  { return mkscale(sc->max_w1, 7.f); }
DI float d_sw2(const Scal* sc)  { return mkscale(sc->max_w2, 7.f); }
DI float d_s1(const Scal* sc)   { return fmaxf((float)sc->max1 * (d_s_in(sc) * d_sw1(sc)), 1e-8f) / 15.f; }
DI float d_s2(const Scal* sc)   { return fmaxf((float)sc->max2 * (d_s1(sc) * d_sw2(sc)), 1e-8f) / 15.f; }

static constexpr int NX   = 32 * 3 * 224 * 224;     // 4,816,896
static constexpr int NP1  = 32 * 32 * 222 * 224;    // y1n bytes (planar rows)
static constexpr int C2_ROWB   = 224 * 32;          // 7168 B per y1n row
static constexpr int C2_HPLANE = 224 * 16;          // 3584 B per ic-half plane
static constexpr int C2V_BLK   = 1120;              // 8 XCD * 140 blocks
static constexpr int C2V_ROWS  = 22;                // out rows per wave (10 vslices)
static constexpr int C1V_BLK   = 2072;              // 8 XCD * 259; 8288 waves = 32*7*37
static constexpr int C1V_ROWS  = 6;                 // out rows per wave (37 vslices)

// ---------------- reduction helpers (up to 8 waves) ----------------
DI float wave_maxf(float v) { for (int o = 32; o; o >>= 1) v = fmaxf(v, __shfl_down(v, o, 64)); return v; }
DI int   wave_maxi(int v)   { for (int o = 32; o; o >>= 1) v = max(v, __shfl_down(v, o, 64));   return v; }

// NOTE: callers pass values >= 0; unused wave slots read as 0.
DI float block_maxf(float v) {
  __shared__ float s[8];
  v = wave_maxf(v);
  int lane = threadIdx.x & 63, w = threadIdx.x >> 6;
  int nw = (int)(blockDim.x >> 6);
  if (!lane) s[w] = v;
  __syncthreads();
  if (threadIdx.x < 64) {
    float t = ((int)threadIdx.x < nw) ? s[threadIdx.x] : 0.f;
    v = wave_maxf(t);
  }
  return v;
}

DI int block_maxi(int v) {
  __shared__ int s[8];
  v = wave_maxi(v);
  int lane = threadIdx.x & 63, w = threadIdx.x >> 6;
  int nw = (int)(blockDim.x >> 6);
  if (!lane) s[w] = v;
  __syncthreads();
  if (threadIdx.x < 64) {
    int t = ((int)threadIdx.x < nw) ? s[threadIdx.x] : 0;
    v = wave_maxi(t);
  }
  return v;
}

// ---------------- stage kernels ----------------
// merged absmax: blocks 0..1023 = x (grid-stride); 1024..1027 = weights
__global__ void k_absmax_xw(const float4* __restrict__ x, int n4,
                            const float* __restrict__ w1, const float* __restrict__ w2,
                            const float* __restrict__ wf1, const float* __restrict__ wf2,
                            Scal* sc) {
  if (blockIdx.x < 1024) {
    float m = 0.f;
    for (int i = blockIdx.x * 256 + threadIdx.x; i < n4; i += 1024 * 256) {
      float4 v = x[i];
      m = fmaxf(m, fmaxf(fmaxf(fabsf(v.x), fabsf(v.y)), fmaxf(fabsf(v.z), fabsf(v.w))));
    }
    m = block_maxf(m);
    if (!threadIdx.x) atomicMax(&sc->max_x, __float_as_uint(m));
    return;
  }
  const float* p; int n; unsigned* slot;
  int wb = blockIdx.x - 1024;
  if (wb == 0)      { p = w1;  n = 864;   slot = &sc->max_w1; }
  else if (wb == 1) { p = w2;  n = 18432; slot = &sc->max_w2; }
  else if (wb == 2) { p = wf1; n = 8192;  slot = &sc->max_wf1; }
  else              { p = wf2; n = 1280;  slot = &sc->max_wf2; }
  float m = 0.f;
  for (int i = threadIdx.x; i < n; i += 256) m = fmaxf(m, fabsf(p[i]));
  m = block_maxf(m);
  if (!threadIdx.x) atomicMax(slot, __float_as_uint(m));
}

// ---------------- conv1 via MFMA: vertical-strip waves, near-zero-LDS -----
// K-order: k = ic*9 + kh*3 + kw (27 taps, 5 zero-pad). A = w1 (32 oc rows),
// B = im2col codes (32 px cols), quantized IN REGISTERS from global x.
// Wave = (img, owg, vslice); walks 6 output rows. Codes held in a 4-bank
// rolling window cw[4][2]; one new input row loaded+quantized per iter,
// prefetched one iter ahead. Weights/bias in 1.3KB LDS staged once.

// pack K-half 0 (k0..15) from tap words s0..s5 (3 valid bytes each)
DI void kpack0(const unsigned* R, v4i& f) {
  f[0] = (int)bperm(R[1], R[0], 0x04020100u);  // s0.b012, s1.b0
  f[1] = (int)bperm(R[2], R[1], 0x05040201u);  // s1.b12, s2.b01
  f[2] = (int)bperm(R[3], R[2], 0x06050402u);  // s2.b2, s3.b012
  f[3] = (int)bperm(R[5], R[4], 0x04020100u);  // s4.b012, s5.b0
}
// pack K-half 1 (k16..31) from tap words s5..s8
DI void kpack1(const unsigned* R, v4i& f) {
  f[0] = (int)bperm(R[1], R[0], 0x05040201u);  // s5.b12, s6.b01
  f[1] = (int)bperm(R[2], R[1], 0x06050402u);  // s6.b2, s7.b012
  f[2] = (int)bperm(0u,   R[3], 0x04020100u);  // s8.b012, 0
  f[3] = 0;                                     // pad k28..31
}

DI v4i conv1_afrag(const unsigned* lw, int oc, int lhalf) {
  unsigned R[6];
  v4i f;
  if (lhalf == 0) {
#pragma unroll
    for (int s = 0; s < 6; ++s) R[s] = lw[oc * 9 + s];
    kpack0(R, f);
  } else {
#pragma unroll
    for (int s = 0; s < 4; ++s) R[s] = lw[oc * 9 + 5 + s];
    kpack1(R, f);
  }
  return f;
}

// weight/bias staging for 256-thread blocks (single barrier by caller)
DI void conv1_wstage(const float* w1, const float* b1, int tid,
                     float s_in, float sw1, unsigned* lw, int* lb) {
  for (int i = tid; i < 288; i += 256) {
    int oc = i / 9, r = i - oc * 9;
    unsigned w = 0;
#pragma unroll
    for (int k = 0; k < 3; ++k) {
      float q = rintf(w1[oc * 27 + r * 3 + k] / sw1);
      q = fminf(fmaxf(q, -8.f), 7.f);
      w |= ((unsigned)((int)q & 255)) << (8 * k);
    }
    lw[i] = w;
  }
  if (tid < 32) lb[tid] = (int)rintf(b1[tid] / (s_in * sw1));
}

// build B-frag for output row t (relative): R[s] = cw[(t+kh)&3][slot]
#define C1_BFRAG(bf, t)                                                    \
  {                                                                        \
    unsigned R[6];                                                         \
    if (lhalf == 0) {                                                      \
      R[0] = cw[(t) & 3][0]; R[1] = cw[((t) + 1) & 3][0];                  \
      R[2] = cw[((t) + 2) & 3][0];                                         \
      R[3] = cw[(t) & 3][1]; R[4] = cw[((t) + 1) & 3][1];                  \
      R[5] = cw[((t) + 2) & 3][1];                                         \
      kpack0(R, bf);                                                       \
    } else {                                                               \
      R[0] = cw[((t) + 2) & 3][0];                                         \
      R[1] = cw[(t) & 3][1]; R[2] = cw[((t) + 1) & 3][1];                  \
      R[3] = cw[((t) + 2) & 3][1];                                         \
      kpack1(R, bf);                                                       \
    }                                                                      \
  }

// load+quantize one input row (relative row index rr, bank bk)
#define C1_LOAD(bk, rr)                                                    \
  {                                                                        \
    const float* r0 = xb + (size_t)(j0 + (rr)) * 224;                      \
    cw[bk][0] = q3(r0, s_in);                                              \
    cw[bk][1] = q3(r0 + 224 * 224, s_in);                                  \
  }

// pass A: MAX ONLY. Blocks >= C1V_BLK pack w2frag (MFMA B-frag layout).
__global__ void __launch_bounds__(256, 4) k_conv1a(
    const float* __restrict__ x, const float* __restrict__ w1,
    const float* __restrict__ b1, const float* __restrict__ w2,
    const Scal* __restrict__ sc, unsigned* __restrict__ w2frag,
    int* __restrict__ max1) {
  int tid = threadIdx.x;
  if (blockIdx.x >= C1V_BLK) {   // 18 blocks: pack w2 into MFMA B-frag layout
    int j = (blockIdx.x - C1V_BLK) * 256 + tid;   // 0..4607
    if (j < 4608) {
      int icq = j & 7; int t = j >> 3;
      int kw = t % 3; t /= 3;
      int kh = t % 3; int oc = t / 3;
      float s = d_sw2(sc);
      unsigned w = 0;
#pragma unroll
      for (int k = 0; k < 4; ++k) {
        int ic = icq * 4 + k;
        float q = rintf(w2[(oc * 32 + ic) * 9 + kh * 3 + kw] / s);
        q = fminf(fmaxf(q, -8.f), 7.f);
        w |= ((unsigned)((int)q & 255)) << (8 * k);
      }
      int tap = kh * 3 + kw;
      int dl = (oc & 31) | ((icq >> 2) << 5);
      w2frag[(((tap * 2) + (oc >> 5)) * 64 + dl) * 4 + (icq & 3)] = w;
    }
    return;
  }

  __shared__ unsigned lw[288];
  __shared__ int lb[32];
  float s_in = d_s_in(sc), sw1 = d_sw1(sc);
  conv1_wstage(w1, b1, tid, s_in, sw1, lw, lb);
  __syncthreads();

  int lane = tid & 63, wv = tid >> 6;
  int lane31 = lane & 31, lhalf = lane >> 5;
  int blk = (int)blockIdx.x;
  int blk2 = (blk & 7) * 259 + (blk >> 3);     // 2072 = 8*259, bijective
  int role = blk2 * 4 + wv;                    // img-major: 259 roles/img
  int img = role / 259;
  int rem = role - img * 259;
  int owg = rem % 7, vs = rem / 7;             // vs 0..36
  int j0 = vs * C1V_ROWS;
  int p = owg * 32 + lane31;
  int pc = (p < 222) ? p : 221;                // clamp loads for edge lanes

  v4i af = conv1_afrag(lw, lane31, lhalf);
  const v4i* lbv = (const v4i*)lb;
  v4i bq[4];
#pragma unroll
  for (int q = 0; q < 4; ++q) bq[q] = lbv[lhalf + 2 * q];

  int icA = lhalf ? 1 : 0;                     // slot0 plane
  const float* xb = x + ((size_t)(img * 3 + icA) * 224) * 224 + pc;

  unsigned cw[4][2];
  C1_LOAD(0, 0); C1_LOAD(1, 1); C1_LOAD(2, 2);

  int mx = 0;
#pragma unroll
  for (int t = 0; t < C1V_ROWS; ++t) {
    if (t < C1V_ROWS - 1) C1_LOAD((t + 3) & 3, t + 3);  // prefetch next row
    v4i bf;
    C1_BFRAG(bf, t);
    v16i acc;
#pragma unroll
    for (int q = 0; q < 4; ++q)
#pragma unroll
      for (int j = 0; j < 4; ++j) acc[4 * q + j] = bq[q][j];
    acc = __builtin_amdgcn_mfma_i32_32x32x32_i8(af, bf, acc, 0, 0, 0);
    if (p < 222) {
#pragma unroll
      for (int r = 0; r < 16; ++r) mx = max(mx, acc[r]);
    }
  }
  mx = block_maxi(max(mx, 0));
  if (!tid) atomicMax(max1, mx);
}

// pass B: recompute acc via MFMA, quantize, store planar codes
// row = [ichalf(2)][224 px][16 oc bytes].
__global__ void __launch_bounds__(256, 4) k_conv1b(
    const float* __restrict__ x, const float* __restrict__ w1,
    const float* __restrict__ b1, const Scal* __restrict__ sc,
    unsigned char* __restrict__ y1n) {
  __shared__ unsigned lw[288];
  __shared__ int lb[32];
  int tid = threadIdx.x;
  float s_in = d_s_in(sc), sw1 = d_sw1(sc);
  conv1_wstage(w1, b1, tid, s_in, sw1, lw, lb);
  __syncthreads();

  int lane = tid & 63, wv = tid >> 6;
  int lane31 = lane & 31, lhalf = lane >> 5;
  int blk = (int)blockIdx.x;
  int blk2 = (blk & 7) * 259 + (blk >> 3);
  int role = blk2 * 4 + wv;
  int img = role / 259;
  int rem = role - img * 259;
  int owg = rem % 7, vs = rem / 7;
  int j0 = vs * C1V_ROWS;
  int p = owg * 32 + lane31;
  int pc = (p < 222) ? p : 221;

  v4i af = conv1_afrag(lw, lane31, lhalf);
  const v4i* lbv = (const v4i*)lb;
  v4i bq[4];
#pragma unroll
  for (int q = 0; q < 4; ++q) bq[q] = lbv[lhalf + 2 * q];

  float h1 = (s_in * sw1) / d_s1(sc);
  int icA = lhalf ? 1 : 0;
  const float* xb = x + ((size_t)(img * 3 + icA) * 224) * 224 + pc;

  unsigned cw[4][2];
  C1_LOAD(0, 0); C1_LOAD(1, 1); C1_LOAD(2, 2);

#pragma unroll
  for (int t = 0; t < C1V_ROWS; ++t) {
    if (t < C1V_ROWS - 1) C1_LOAD((t + 3) & 3, t + 3);
    v4i bf;
    C1_BFRAG(bf, t);
    v16i acc;
#pragma unroll
    for (int q = 0; q < 4; ++q)
#pragma unroll
      for (int j = 0; j < 4; ++j) acc[4 * q + j] = bq[q][j];
    acc = __builtin_amdgcn_mfma_i32_32x32x32_i8(af, bf, acc, 0, 0, 0);
    if (p < 222) {
      size_t rowb = (size_t)(img * 222 + j0 + t) * C2_ROWB;
      unsigned char* dst0 = y1n + rowb + (size_t)p * 16;
#pragma unroll
      for (int q = 0; q < 4; ++q) {
        int oc0 = 8 * q + 4 * lhalf;       // C row = (r&3)+8*(r>>2)+4*lhalf
        unsigned cwd = 0;
#pragma unroll
        for (int j = 0; j < 4; ++j)
          cwd |= ((unsigned)(int)qclamp(acc[4 * q + j], h1)) << (8 * j);
        *(unsigned*)(dst0 + (oc0 >> 4) * C2_HPLANE + (oc0 & 15)) = cwd;
      }
    }
  }
}

// ---------------- conv2: vertical-strip waves + register rolling window ---
// Wave = (img, owg, oc-half, vslice); walks 22 consecutive output rows.
// 9 weight B-frags in registers; A held in a 4-bank register window A[4][3].
// Scalar bias + per-row acc init.

__global__ void __launch_bounds__(256, 4) k_conv2a(
    const unsigned char* __restrict__ y1n, const unsigned* __restrict__ w2frag,
    const float* __restrict__ b2, const Scal* __restrict__ sc, int* __restrict__ max2) {
  int tid = threadIdx.x;
  int lane = tid & 63, wv = tid >> 6;
  int lane31 = lane & 31, lhalf = lane >> 5;
  int blk = (int)blockIdx.x;
  int blk2 = (blk & 7) * 140 + (blk >> 3);     // 1120 = 8*140, bijective
  int role = blk2 * 4 + wv;                    // img-major: 140 roles/img
  int img = role / 140;
  int rem = role - img * 140;
  int owg = rem % 7;
  int t7 = rem / 7;
  int hh = t7 & 1;
  int vs = t7 >> 1;
  int j0 = vs * C2V_ROWS;
  int ow0 = owg * 32;

  v4i wb[9];
  const v4i* gW = (const v4i*)w2frag;
#pragma unroll
  for (int t = 0; t < 9; ++t) wb[t] = gW[(t * 2 + hh) * 64 + lane];

  float sb = d_s1(sc) * d_sw2(sc);
  int bias = (int)rintf(b2[hh * 32 + lane31] / sb);

  const unsigned char* base = y1n + (size_t)(img * 222 + j0) * C2_ROWB
                              + (size_t)lhalf * C2_HPLANE
                              + (size_t)(ow0 + lane31) * 16;
  v4i A[4][3];
#pragma unroll
  for (int r = 0; r < 3; ++r)
#pragma unroll
    for (int kw = 0; kw < 3; ++kw)
      A[r][kw] = *(const v4i*)(base + (size_t)r * C2_ROWB + kw * 16);

  int mx = 0;
#pragma unroll
  for (int jj = 0; jj < C2V_ROWS; ++jj) {
    if (jj < C2V_ROWS - 1) {                   // prefetch row jj+3 (<= 23)
      const unsigned char* rp = base + (size_t)(jj + 3) * C2_ROWB;
#pragma unroll
      for (int kw = 0; kw < 3; ++kw)
        A[(jj + 3) & 3][kw] = *(const v4i*)(rp + kw * 16);
    }
    v16i acc;
#pragma unroll
    for (int r = 0; r < 16; ++r) acc[r] = bias;
#pragma unroll
    for (int kh = 0; kh < 3; ++kh)
#pragma unroll
      for (int kw = 0; kw < 3; ++kw)
        acc = __builtin_amdgcn_mfma_i32_32x32x32_i8(A[(jj + kh) & 3][kw], wb[kh * 3 + kw], acc, 0, 0, 0);

    if (owg != 6) {
#pragma unroll
      for (int r = 0; r < 16; ++r) mx = max(mx, acc[r]);
    } else {
#pragma unroll
      for (int r = 0; r < 16; ++r) {
        int m = (r & 3) + 8 * (r >> 2) + 4 * lhalf;
        if (ow0 + m < 220) mx = max(mx, acc[r]);
      }
    }
  }
  mx = block_maxi(max(mx, 0));
  if (!tid) atomicMax(max2, mx);
}

__global__ void __launch_bounds__(256, 4) k_conv2b(
    const unsigned char* __restrict__ y1n, const unsigned* __restrict__ w2frag,
    const float* __restrict__ b2, const Scal* __restrict__ sc,
    int* __restrict__ pooled_i) {
  int tid = threadIdx.x;
  int lane = tid & 63, wv = tid >> 6;
  int lane31 = lane & 31, lhalf = lane >> 5;
  int blk = (int)blockIdx.x;
  int blk2 = (blk & 7) * 140 + (blk >> 3);
  int role = blk2 * 4 + wv;
  int img = role / 140;
  int rem = role - img * 140;
  int owg = rem % 7;
  int t7 = rem / 7;
  int hh = t7 & 1;
  int vs = t7 >> 1;
  int j0 = vs * C2V_ROWS;
  int ow0 = owg * 32;

  v4i wb[9];
  const v4i* gW = (const v4i*)w2frag;
#pragma unroll
  for (int t = 0; t < 9; ++t) wb[t] = gW[(t * 2 + hh) * 64 + lane];

  float sb = d_s1(sc) * d_sw2(sc);
  int bias = (int)rintf(b2[hh * 32 + lane31] / sb);
  float h1 = sb * (1.0f / d_s2(sc));

  const unsigned char* base = y1n + (size_t)(img * 222 + j0) * C2_ROWB
                              + (size_t)lhalf * C2_HPLANE
                              + (size_t)(ow0 + lane31) * 16;
  v4i A[4][3];
#pragma unroll
  for (int r = 0; r < 3; ++r)
#pragma unroll
    for (int kw = 0; kw < 3; ++kw)
      A[r][kw] = *(const v4i*)(base + (size_t)r * C2_ROWB + kw * 16);

  float psum = 0.f;
#pragma unroll
  for (int jj = 0; jj < C2V_ROWS; ++jj) {
    if (jj < C2V_ROWS - 1) {                   // prefetch row jj+3 (<= 23)
      const unsigned char* rp = base + (size_t)(jj + 3) * C2_ROWB;
#pragma unroll
      for (int kw = 0; kw < 3; ++kw)
        A[(jj + 3) & 3][kw] = *(const v4i*)(rp + kw * 16);
    }
    v16i acc;
#pragma unroll
    for (int r = 0; r < 16; ++r) acc[r] = bias;
#pragma unroll
    for (int kh = 0; kh < 3; ++kh)
#pragma unroll
      for (int kw = 0; kw < 3; ++kw)
        acc = __builtin_amdgcn_mfma_i32_32x32x32_i8(A[(jj + kh) & 3][kw], wb[kh * 3 + kw], acc, 0, 0, 0);

    if (owg != 6) {
#pragma unroll
      for (int r = 0; r < 16; ++r) psum += qclamp(acc[r], h1);
    } else {
#pragma unroll
      for (int r = 0; r < 16; ++r) {
        int m = (r & 3) + 8 * (r >> 2) + 4 * lhalf;
        if (ow0 + m < 220) psum += qclamp(acc[r], h1);
      }
    }
  }
  int s = (int)psum;
  s += __shfl_down(s, 32, 64);                 // combine px-halves (same oc)
  if (lhalf == 0) atomicAdd(&pooled_i[img * 64 + hh * 32 + lane31], s);
}

// ---------------- FC head, split for parallelism --------------------------
// fc1: 32 blocks (1/image) x 128 thr; thread j computes y3[b][j] with
// inline wf1 quantization (64 MACs), relu, writes y3g, atomicMax of max.
__global__ void __launch_bounds__(128) k_fc1(
    const int* __restrict__ pooled_i, const float* __restrict__ wf1,
    const float* __restrict__ bf1, Scal* __restrict__ sc,
    float* __restrict__ y3g) {
  __shared__ float xrow[64];
  __shared__ float red[2];
  int tid = threadIdx.x;
  int b = (int)blockIdx.x;
  float swf1 = mkscale(sc->max_wf1, 7.f);
  float s2 = d_s2(sc);
  if (tid < 64) xrow[tid] = (float)pooled_i[b * 64 + tid] * s2 / 48400.0f;
  __syncthreads();
  float sb1 = s2 * swf1;
  float acc = rintf(bf1[tid] / sb1) * sb1;
  const float* wrow = wf1 + tid * 64;
#pragma unroll 8
  for (int k = 0; k < 64; ++k) {
    float q = rintf(wrow[k] / swf1);
    q = fminf(fmaxf(q, -8.f), 7.f);
    acc += xrow[k] * (q * swf1);
  }
  float r = fmaxf(acc, 0.f);
  y3g[b * 128 + tid] = r;
  float m = wave_maxf(r);
  int lane = tid & 63, w = tid >> 6;
  if (!lane) red[w] = m;
  __syncthreads();
  if (!tid) {
    float t = fmaxf(red[0], red[1]);
    atomicMax(&sc->max3, __float_as_uint(t));   // r >= 0: uint order == float order
  }
}

// fc2: 1 block x 320 thr; quantized fc2 + log_softmax.
__global__ void __launch_bounds__(320) k_fc2(
    const float* __restrict__ y3g, const float* __restrict__ wf2,
    const float* __restrict__ bf2, const Scal* __restrict__ sc,
    float* __restrict__ out) {
  __shared__ float zz[320];
  int tid = threadIdx.x;
  float swf2 = mkscale(sc->max_wf2, 7.f);
  float s3 = fmaxf(__uint_as_float(sc->max3), 1e-8f) / 15.f;
  float sb2 = s3 * swf2;
  {
    int b = tid / 10, j = tid - b * 10;
    float acc = rintf(bf2[j] / sb2) * sb2;
    const float* yy = y3g + b * 128;
    const float* wrow = wf2 + j * 128;
#pragma unroll 16
    for (int k = 0; k < 128; ++k) {
      float q = rintf(yy[k] / s3);
      q = fminf(fmaxf(q, 0.f), 15.f);
      float wv = rintf(wrow[k] / swf2);
      wv = fminf(fmaxf(wv, -8.f), 7.f);
      acc += (q * s3) * (wv * swf2);
    }
    zz[tid] = acc;
  }
  __syncthreads();
  if (tid < 32) {
    const float* z = &zz[tid * 10];
    float mm = z[0];
    for (int k = 1; k < 10; ++k) mm = fmaxf(mm, z[k]);
    float ssum = 0.f;
    for (int k = 0; k < 10; ++k) ssum += expf(z[k] - mm);
    float l = mm + logf(ssum);
    for (int k = 0; k < 10; ++k) out[tid * 10 + k] = z[k] - l;
  }
}

extern "C" void kernel_launch(void* const* d_in, const int* in_sizes, int n_in,
                              void* d_out, int out_size, void* d_ws, size_t ws_size,
                              hipStream_t stream) {
  const float* x   = (const float*)d_in[0];
  const float* w1  = (const float*)d_in[1];
  const float* b1  = (const float*)d_in[2];
  const float* w2  = (const float*)d_in[3];
  const float* b2  = (const float*)d_in[4];
  const float* wf1 = (const float*)d_in[5];
  const float* bf1 = (const float*)d_in[6];
  const float* wf2 = (const float*)d_in[7];
  const float* bf2 = (const float*)d_in[8];
  float* out = (float*)d_out;

  char* ws = (char*)d_ws;
  Scal* sc = (Scal*)ws;
  int* pooled_i = (int*)(ws + 1024);            // sc + pooled zeroed by ONE memset
  size_t off = 1024 + 8192;
  unsigned* w2frag = (unsigned*)(ws + off);     off += 4608 * 4;          // MFMA B-frag layout
  float* y3g = (float*)(ws + off);              off += 32 * 128 * 4;      // fc1 output
  off = (off + 255) & ~(size_t)255;
  unsigned char* y1n = (unsigned char*)(ws + off); off += (size_t)NP1 + 256; // planar codes + slack
  (void)ws_size; (void)in_sizes; (void)n_in; (void)out_size;

  hipMemsetAsync(ws, 0, 1024 + 8192, stream);
  k_absmax_xw<<<1028, 256, 0, stream>>>((const float4*)x, NX / 4, w1, w2, wf1, wf2, sc);
  k_conv1a<<<C1V_BLK + 18, 256, 0, stream>>>(x, w1, b1, w2, sc, w2frag, &sc->max1);
  k_conv1b<<<C1V_BLK, 256, 0, stream>>>(x, w1, b1, sc, y1n);
  k_conv2a<<<C2V_BLK, 256, 0, stream>>>(y1n, w2frag, b2, sc, &sc->max2);
  k_conv2b<<<C2V_BLK, 256, 0, stream>>>(y1n, w2frag, b2, sc, pooled_i);
  k_fc1<<<32, 128, 0, stream>>>(pooled_i, wf1, bf1, sc, y3g);
  k_fc2<<<1, 320, 0, stream>>>(y3g, wf2, bf2, sc, out);
}

// Round 17
// 223.049 us; speedup vs baseline: 1.1324x; 1.0852x over previous
//
#include <hip/hip_runtime.h>
#include <cstdint>
#include <cstddef>

#define DI __device__ __forceinline__

typedef int v4i  __attribute__((ext_vector_type(4)));
typedef int v16i __attribute__((ext_vector_type(16)));

#if defined(__has_builtin)
#if __has_builtin(__builtin_amdgcn_alignbyte)
#define HAS_ALIGNBYTE 1
#endif
#if __has_builtin(__builtin_amdgcn_perm)
#define HAS_PERM 1
#endif
#endif

DI unsigned alignb(unsigned hi, unsigned lo, int sh) {  // bytes (hi:lo) >> 8*sh
#ifdef HAS_ALIGNBYTE
  return __builtin_amdgcn_alignbyte(hi, lo, sh);
#else
  return sh ? ((lo >> (8 * sh)) | (hi << (32 - 8 * sh))) : lo;
#endif
}

// byte permute over (hi:lo); sel byte v in 0..3 -> lo.byte[v], 4..7 -> hi.byte[v-4]
DI unsigned bperm(unsigned hi, unsigned lo, unsigned sel) {
#ifdef HAS_PERM
  return __builtin_amdgcn_perm(hi, lo, sel);
#else
  unsigned r = 0;
#pragma unroll
  for (int i = 0; i < 4; ++i) {
    unsigned s = (sel >> (8 * i)) & 255u;
    unsigned b = (s < 4) ? (lo >> (8 * s)) : (hi >> (8 * (s - 4)));
    r |= (b & 255u) << (8 * i);
  }
  return r;
#endif
}

DI float qclamp(int a, float h) {  // clamp(rint(a*h), 0, 15) as float
  return fminf(fmaxf(rintf((float)a * h), 0.f), 15.f);
}

DI unsigned pack4(float4 v, float s) {  // quantize 4 floats -> 4 int8 codes
  float f[4] = {v.x, v.y, v.z, v.w};
  unsigned w = 0;
#pragma unroll
  for (int k = 0; k < 4; ++k) {
    float q = rintf(f[k] / s);
    q = fminf(fmaxf(q, -8.f), 7.f);
    w |= ((unsigned)((int)q & 255)) << (8 * k);
  }
  return w;
}

// ---------------- scalar block in workspace ----------------
struct Scal {
  unsigned max_x, max_w1, max_w2, max_wf1, max_wf2;  // float bits (abs-max, >=0)
  int max1, max2;
  unsigned max3;                                      // relu(fc1) max, float bits
};

DI float mkscale(unsigned bits, float d) { return fmaxf(__uint_as_float(bits), 1e-8f) / d; }
DI float d_s_in(const Scal* sc) { return mkscale(sc->max_x, 7.f); }
DI float d_sw1(const Scal* sc)  { return mkscale(sc->max_w1, 7.f); }
DI float d_sw2(const Scal* sc)  { return mkscale(sc->max_w2, 7.f); }
DI float d_s1(const Scal* sc)   { return fmaxf((float)sc->max1 * (d_s_in(sc) * d_sw1(sc)), 1e-8f) / 15.f; }
DI float d_s2(const Scal* sc)   { return fmaxf((float)sc->max2 * (d_s1(sc) * d_sw2(sc)), 1e-8f) / 15.f; }

static constexpr int NX   = 32 * 3 * 224 * 224;     // 4,816,896
static constexpr int NP1  = 32 * 32 * 222 * 224;    // y1n bytes (planar rows)
static constexpr int C2_ROWB   = 224 * 32;          // 7168 B per y1n row
static constexpr int C2_HPLANE = 224 * 16;          // 3584 B per ic-half plane
static constexpr int C2V_BLK   = 1120;              // 8 XCD * 140 blocks
static constexpr int C2V_ROWS  = 22;                // out rows per wave (10 vslices)

// ---------------- reduction helpers (up to 8 waves) ----------------
DI float wave_maxf(float v) { for (int o = 32; o; o >>= 1) v = fmaxf(v, __shfl_down(v, o, 64)); return v; }
DI int   wave_maxi(int v)   { for (int o = 32; o; o >>= 1) v = max(v, __shfl_down(v, o, 64));   return v; }

// NOTE: callers pass values >= 0; unused wave slots read as 0.
DI float block_maxf(float v) {
  __shared__ float s[8];
  v = wave_maxf(v);
  int lane = threadIdx.x & 63, w = threadIdx.x >> 6;
  int nw = (int)(blockDim.x >> 6);
  if (!lane) s[w] = v;
  __syncthreads();
  if (threadIdx.x < 64) {
    float t = ((int)threadIdx.x < nw) ? s[threadIdx.x] : 0.f;
    v = wave_maxf(t);
  }
  return v;
}

DI int block_maxi(int v) {
  __shared__ int s[8];
  v = wave_maxi(v);
  int lane = threadIdx.x & 63, w = threadIdx.x >> 6;
  int nw = (int)(blockDim.x >> 6);
  if (!lane) s[w] = v;
  __syncthreads();
  if (threadIdx.x < 64) {
    int t = ((int)threadIdx.x < nw) ? s[threadIdx.x] : 0;
    v = wave_maxi(t);
  }
  return v;
}

// ---------------- stage kernels ----------------
// merged absmax: blocks 0..1023 = x (grid-stride); 1024..1027 = weights
__global__ void k_absmax_xw(const float4* __restrict__ x, int n4,
                            const float* __restrict__ w1, const float* __restrict__ w2,
                            const float* __restrict__ wf1, const float* __restrict__ wf2,
                            Scal* sc) {
  if (blockIdx.x < 1024) {
    float m = 0.f;
    for (int i = blockIdx.x * 256 + threadIdx.x; i < n4; i += 1024 * 256) {
      float4 v = x[i];
      m = fmaxf(m, fmaxf(fmaxf(fabsf(v.x), fabsf(v.y)), fmaxf(fabsf(v.z), fabsf(v.w))));
    }
    m = block_maxf(m);
    if (!threadIdx.x) atomicMax(&sc->max_x, __float_as_uint(m));
    return;
  }
  const float* p; int n; unsigned* slot;
  int wb = blockIdx.x - 1024;
  if (wb == 0)      { p = w1;  n = 864;   slot = &sc->max_w1; }
  else if (wb == 1) { p = w2;  n = 18432; slot = &sc->max_w2; }
  else if (wb == 2) { p = wf1; n = 8192;  slot = &sc->max_wf1; }
  else              { p = wf2; n = 1280;  slot = &sc->max_wf2; }
  float m = 0.f;
  for (int i = threadIdx.x; i < n; i += 256) m = fmaxf(m, fabsf(p[i]));
  m = block_maxf(m);
  if (!threadIdx.x) atomicMax(slot, __float_as_uint(m));
}

// ---------------- conv1 via MFMA (i32_32x32x32_i8), LDS-staged ------------
// K-order: k = ic*9 + kh*3 + kw (27 taps, 5 zero-pad). A = w1 (32 oc rows),
// B = im2col activations (32 px cols). One MFMA per 32px x 32oc x fullK tile.
// Block: 448 thr = 7 waves = 7 px-tiles, 6 output rows each (42 MFMA).
// C layout (validated): row oc = (r&3)+8*(r>>2)+4*lhalf, col = px = lane&31.

// pack K-half 0 (k0..15) from tap words s0..s5 (3 valid bytes each)
DI void kpack0(const unsigned* R, v4i& f) {
  f[0] = (int)bperm(R[1], R[0], 0x04020100u);  // s0.b012, s1.b0
  f[1] = (int)bperm(R[2], R[1], 0x05040201u);  // s1.b12, s2.b01
  f[2] = (int)bperm(R[3], R[2], 0x06050402u);  // s2.b2, s3.b012
  f[3] = (int)bperm(R[5], R[4], 0x04020100u);  // s4.b012, s5.b0
}
// pack K-half 1 (k16..31) from tap words s5..s8
DI void kpack1(const unsigned* R, v4i& f) {
  f[0] = (int)bperm(R[1], R[0], 0x05040201u);  // s5.b12, s6.b01
  f[1] = (int)bperm(R[2], R[1], 0x06050402u);  // s6.b2, s7.b012
  f[2] = (int)bperm(0u,   R[3], 0x04020100u);  // s8.b012, 0
  f[3] = 0;                                     // pad k28..31
}

DI v4i conv1_afrag(const unsigned* lw, int oc, int lhalf) {
  unsigned R[6];
  v4i f;
  if (lhalf == 0) {
#pragma unroll
    for (int s = 0; s < 6; ++s) R[s] = lw[oc * 9 + s];
    kpack0(R, f);
  } else {
#pragma unroll
    for (int s = 0; s < 4; ++s) R[s] = lw[oc * 9 + 5 + s];
    kpack1(R, f);
  }
  return f;
}

DI v4i conv1_bfrag(const signed char* lx, int oh_l, int qb, int sh, int lhalf) {
  unsigned R[6];
  v4i f;
  if (lhalf == 0) {
#pragma unroll
    for (int s = 0; s < 6; ++s) {          // segs (ic0,kh0..2),(ic1,kh0..2)
      int ic = s / 3, kh = s - ic * 3;
      const signed char* base = lx + (ic * 8 + oh_l + kh) * 224 + qb;
      unsigned d0 = *(const unsigned*)base;
      unsigned d1 = *(const unsigned*)(base + 4);
      R[s] = alignb(d1, d0, sh);
    }
    kpack0(R, f);
  } else {
#pragma unroll
    for (int s = 0; s < 4; ++s) {          // segs (ic1,kh2),(ic2,kh0..2)
      int seg = 5 + s;
      int ic = seg / 3, kh = seg - ic * 3;
      const signed char* base = lx + (ic * 8 + oh_l + kh) * 224 + qb;
      unsigned d0 = *(const unsigned*)base;
      unsigned d1 = *(const unsigned*)(base + 4);
      R[s] = alignb(d1, d0, sh);
    }
    kpack1(R, f);
  }
  return f;
}

// shared staging: w1 codes (288 words), bias, x codes (1344 words = 3/thr)
DI void conv1_stage(const float4* x, const float* w1, const float* b1,
                    int b, int oh0, int tid, float s_in, float sw1,
                    signed char* lx, unsigned* lw, int* lb) {
  for (int i = tid; i < 288; i += 448) {
    int oc = i / 9, r = i - oc * 9;
    unsigned w = 0;
#pragma unroll
    for (int k = 0; k < 3; ++k) {
      float q = rintf(w1[oc * 27 + r * 3 + k] / sw1);
      q = fminf(fmaxf(q, -8.f), 7.f);
      w |= ((unsigned)((int)q & 255)) << (8 * k);
    }
    lw[i] = w;
  }
  if (tid < 32) lb[tid] = (int)rintf(b1[tid] / (s_in * sw1));
  const float4* src = x + (size_t)b * 3 * 224 * 56;
  unsigned* dst = (unsigned*)lx;
#pragma unroll
  for (int it = 0; it < 3; ++it) {
    int i = it * 448 + tid;               // 1344 = 3*448 exact
    int row = i / 56, d = i - row * 56;   // row = ic*8 + r
    int ic = row >> 3, r = row & 7;
    dst[i] = pack4(src[(ic * 224 + (oh0 + r)) * 56 + d], s_in);
  }
}

// pass A: MAX ONLY. Blocks >= 1184 pack w2frag (MFMA B-frag layout).
__global__ void __launch_bounds__(448) k_conv1a(
    const float4* __restrict__ x, const float* __restrict__ w1,
    const float* __restrict__ b1, const float* __restrict__ w2,
    const Scal* __restrict__ sc, unsigned* __restrict__ w2frag,
    int* __restrict__ max1) {
  int tid = threadIdx.x;
  if (blockIdx.x >= 1184) {   // 11 blocks: pack w2 into MFMA B-frag layout
    int j = (blockIdx.x - 1184) * 448 + tid;   // 0..4607
    if (j < 4608) {
      int icq = j & 7; int t = j >> 3;
      int kw = t % 3; t /= 3;
      int kh = t % 3; int oc = t / 3;
      float s = d_sw2(sc);
      unsigned w = 0;
#pragma unroll
      for (int k = 0; k < 4; ++k) {
        int ic = icq * 4 + k;
        float q = rintf(w2[(oc * 32 + ic) * 9 + kh * 3 + kw] / s);
        q = fminf(fmaxf(q, -8.f), 7.f);
        w |= ((unsigned)((int)q & 255)) << (8 * k);
      }
      int tap = kh * 3 + kw;
      int dl = (oc & 31) | ((icq >> 2) << 5);
      w2frag[(((tap * 2) + (oc >> 5)) * 64 + dl) * 4 + (icq & 3)] = w;
    }
    return;
  }

  __shared__ signed char lx[3 * 8 * 224 + 16];
  __shared__ unsigned lw[288];
  __shared__ int lb[32];
  int strip = blockIdx.x % 37;   // 0..36
  int b = blockIdx.x / 37;       // 0..31
  int oh0 = strip * 6;
  float s_in = d_s_in(sc), sw1 = d_sw1(sc);
  conv1_stage(x, w1, b1, b, oh0, tid, s_in, sw1, lx, lw, lb);
  __syncthreads();

  int lane = tid & 63, wv = tid >> 6;
  int lane31 = lane & 31, lhalf = lane >> 5;
  int p = wv * 32 + lane31;
  int qb = p & ~3, sh = p & 3;
  v4i af = conv1_afrag(lw, lane31, lhalf);
  const v4i* lbv = (const v4i*)lb;
  v4i bq[4];
#pragma unroll
  for (int q = 0; q < 4; ++q) bq[q] = lbv[lhalf + 2 * q];

  int mx = 0;
#pragma unroll
  for (int oh_l = 0; oh_l < 6; ++oh_l) {
    v4i bf = conv1_bfrag(lx, oh_l, qb, sh, lhalf);
    v16i acc;
#pragma unroll
    for (int q = 0; q < 4; ++q)
#pragma unroll
      for (int j = 0; j < 4; ++j) acc[4 * q + j] = bq[q][j];
    acc = __builtin_amdgcn_mfma_i32_32x32x32_i8(af, bf, acc, 0, 0, 0);
    if (p < 222) {
#pragma unroll
      for (int r = 0; r < 16; ++r) mx = max(mx, acc[r]);
    }
  }
  mx = block_maxi(max(mx, 0));
  if (!tid) atomicMax(max1, mx);
}

// pass B: recompute acc via MFMA, quantize, store planar codes
// row = [ichalf(2)][224 px][16 oc bytes].
__global__ void __launch_bounds__(448) k_conv1b(
    const float4* __restrict__ x, const float* __restrict__ w1,
    const float* __restrict__ b1, const Scal* __restrict__ sc,
    unsigned char* __restrict__ y1n) {
  __shared__ signed char lx[3 * 8 * 224 + 16];
  __shared__ unsigned lw[288];
  __shared__ int lb[32];
  int tid = threadIdx.x;
  int strip = blockIdx.x % 37;
  int b = blockIdx.x / 37;
  int oh0 = strip * 6;
  float s_in = d_s_in(sc), sw1 = d_sw1(sc);
  conv1_stage(x, w1, b1, b, oh0, tid, s_in, sw1, lx, lw, lb);
  __syncthreads();

  int lane = tid & 63, wv = tid >> 6;
  int lane31 = lane & 31, lhalf = lane >> 5;
  int p = wv * 32 + lane31;
  int qb = p & ~3, sh = p & 3;
  v4i af = conv1_afrag(lw, lane31, lhalf);
  const v4i* lbv = (const v4i*)lb;
  v4i bq[4];
#pragma unroll
  for (int q = 0; q < 4; ++q) bq[q] = lbv[lhalf + 2 * q];

  float h1 = (s_in * sw1) / d_s1(sc);

#pragma unroll
  for (int oh_l = 0; oh_l < 6; ++oh_l) {
    v4i bf = conv1_bfrag(lx, oh_l, qb, sh, lhalf);
    v16i acc;
#pragma unroll
    for (int q = 0; q < 4; ++q)
#pragma unroll
      for (int j = 0; j < 4; ++j) acc[4 * q + j] = bq[q][j];
    acc = __builtin_amdgcn_mfma_i32_32x32x32_i8(af, bf, acc, 0, 0, 0);
    if (p < 222) {
      size_t rowb = (size_t)(b * 222 + oh0 + oh_l) * C2_ROWB;
      unsigned char* dst0 = y1n + rowb + (size_t)p * 16;
#pragma unroll
      for (int q = 0; q < 4; ++q) {
        int oc0 = 8 * q + 4 * lhalf;       // C row = (r&3)+8*(r>>2)+4*lhalf
        unsigned cw = 0;
#pragma unroll
        for (int j = 0; j < 4; ++j)
          cw |= ((unsigned)(int)qclamp(acc[4 * q + j], h1)) << (8 * j);
        *(unsigned*)(dst0 + (oc0 >> 4) * C2_HPLANE + (oc0 & 15)) = cw;
      }
    }
  }
}

// ---------------- conv2: vertical-strip waves + register rolling window ---
// Wave = (img, owg, oc-half, vslice); walks 22 consecutive output rows.
// 9 weight B-frags in registers; A held in a 4-bank register window A[4][3].
// Scalar bias + per-row acc init (minimal persistent registers).

__global__ void __launch_bounds__(256, 4) k_conv2a(
    const unsigned char* __restrict__ y1n, const unsigned* __restrict__ w2frag,
    const float* __restrict__ b2, const Scal* __restrict__ sc, int* __restrict__ max2) {
  int tid = threadIdx.x;
  int lane = tid & 63, wv = tid >> 6;
  int lane31 = lane & 31, lhalf = lane >> 5;
  int blk = (int)blockIdx.x;
  int blk2 = (blk & 7) * 140 + (blk >> 3);     // 1120 = 8*140, bijective
  int role = blk2 * 4 + wv;                    // img-major: 140 roles/img
  int img = role / 140;
  int rem = role - img * 140;
  int owg = rem % 7;
  int t7 = rem / 7;
  int hh = t7 & 1;
  int vs = t7 >> 1;
  int j0 = vs * C2V_ROWS;
  int ow0 = owg * 32;

  v4i wb[9];
  const v4i* gW = (const v4i*)w2frag;
#pragma unroll
  for (int t = 0; t < 9; ++t) wb[t] = gW[(t * 2 + hh) * 64 + lane];

  float sb = d_s1(sc) * d_sw2(sc);
  int bias = (int)rintf(b2[hh * 32 + lane31] / sb);

  const unsigned char* base = y1n + (size_t)(img * 222 + j0) * C2_ROWB
                              + (size_t)lhalf * C2_HPLANE
                              + (size_t)(ow0 + lane31) * 16;
  v4i A[4][3];
#pragma unroll
  for (int r = 0; r < 3; ++r)
#pragma unroll
    for (int kw = 0; kw < 3; ++kw)
      A[r][kw] = *(const v4i*)(base + (size_t)r * C2_ROWB + kw * 16);

  int mx = 0;
#pragma unroll
  for (int jj = 0; jj < C2V_ROWS; ++jj) {
    if (jj < C2V_ROWS - 1) {                   // prefetch row jj+3 (<= 23)
      const unsigned char* rp = base + (size_t)(jj + 3) * C2_ROWB;
#pragma unroll
      for (int kw = 0; kw < 3; ++kw)
        A[(jj + 3) & 3][kw] = *(const v4i*)(rp + kw * 16);
    }
    v16i acc;
#pragma unroll
    for (int r = 0; r < 16; ++r) acc[r] = bias;
#pragma unroll
    for (int kh = 0; kh < 3; ++kh)
#pragma unroll
      for (int kw = 0; kw < 3; ++kw)
        acc = __builtin_amdgcn_mfma_i32_32x32x32_i8(A[(jj + kh) & 3][kw], wb[kh * 3 + kw], acc, 0, 0, 0);

    if (owg != 6) {
#pragma unroll
      for (int r = 0; r < 16; ++r) mx = max(mx, acc[r]);
    } else {
#pragma unroll
      for (int r = 0; r < 16; ++r) {
        int m = (r & 3) + 8 * (r >> 2) + 4 * lhalf;
        if (ow0 + m < 220) mx = max(mx, acc[r]);
      }
    }
  }
  mx = block_maxi(max(mx, 0));
  if (!tid) atomicMax(max2, mx);
}

__global__ void __launch_bounds__(256, 4) k_conv2b(
    const unsigned char* __restrict__ y1n, const unsigned* __restrict__ w2frag,
    const float* __restrict__ b2, const Scal* __restrict__ sc,
    int* __restrict__ pooled_i) {
  int tid = threadIdx.x;
  int lane = tid & 63, wv = tid >> 6;
  int lane31 = lane & 31, lhalf = lane >> 5;
  int blk = (int)blockIdx.x;
  int blk2 = (blk & 7) * 140 + (blk >> 3);
  int role = blk2 * 4 + wv;
  int img = role / 140;
  int rem = role - img * 140;
  int owg = rem % 7;
  int t7 = rem / 7;
  int hh = t7 & 1;
  int vs = t7 >> 1;
  int j0 = vs * C2V_ROWS;
  int ow0 = owg * 32;

  v4i wb[9];
  const v4i* gW = (const v4i*)w2frag;
#pragma unroll
  for (int t = 0; t < 9; ++t) wb[t] = gW[(t * 2 + hh) * 64 + lane];

  float sb = d_s1(sc) * d_sw2(sc);
  int bias = (int)rintf(b2[hh * 32 + lane31] / sb);
  float h1 = sb * (1.0f / d_s2(sc));

  const unsigned char* base = y1n + (size_t)(img * 222 + j0) * C2_ROWB
                              + (size_t)lhalf * C2_HPLANE
                              + (size_t)(ow0 + lane31) * 16;
  v4i A[4][3];
#pragma unroll
  for (int r = 0; r < 3; ++r)
#pragma unroll
    for (int kw = 0; kw < 3; ++kw)
      A[r][kw] = *(const v4i*)(base + (size_t)r * C2_ROWB + kw * 16);

  float psum = 0.f;
#pragma unroll
  for (int jj = 0; jj < C2V_ROWS; ++jj) {
    if (jj < C2V_ROWS - 1) {                   // prefetch row jj+3 (<= 23)
      const unsigned char* rp = base + (size_t)(jj + 3) * C2_ROWB;
#pragma unroll
      for (int kw = 0; kw < 3; ++kw)
        A[(jj + 3) & 3][kw] = *(const v4i*)(rp + kw * 16);
    }
    v16i acc;
#pragma unroll
    for (int r = 0; r < 16; ++r) acc[r] = bias;
#pragma unroll
    for (int kh = 0; kh < 3; ++kh)
#pragma unroll
      for (int kw = 0; kw < 3; ++kw)
        acc = __builtin_amdgcn_mfma_i32_32x32x32_i8(A[(jj + kh) & 3][kw], wb[kh * 3 + kw], acc, 0, 0, 0);

    if (owg != 6) {
#pragma unroll
      for (int r = 0; r < 16; ++r) psum += qclamp(acc[r], h1);
    } else {
#pragma unroll
      for (int r = 0; r < 16; ++r) {
        int m = (r & 3) + 8 * (r >> 2) + 4 * lhalf;
        if (ow0 + m < 220) psum += qclamp(acc[r], h1);
      }
    }
  }
  int s = (int)psum;
  s += __shfl_down(s, 32, 64);                 // combine px-halves (same oc)
  if (lhalf == 0) atomicAdd(&pooled_i[img * 64 + hh * 32 + lane31], s);
}

// ---------------- FC head, split for parallelism --------------------------
// fc1: 32 blocks (1/image) x 128 thr; thread j computes y3[b][j] with
// inline wf1 quantization (64 MACs), relu, writes y3g, atomicMax of max.
__global__ void __launch_bounds__(128) k_fc1(
    const int* __restrict__ pooled_i, const float* __restrict__ wf1,
    const float* __restrict__ bf1, Scal* __restrict__ sc,
    float* __restrict__ y3g) {
  __shared__ float xrow[64];
  __shared__ float red[2];
  int tid = threadIdx.x;
  int b = (int)blockIdx.x;
  float swf1 = mkscale(sc->max_wf1, 7.f);
  float s2 = d_s2(sc);
  if (tid < 64) xrow[tid] = (float)pooled_i[b * 64 + tid] * s2 / 48400.0f;
  __syncthreads();
  float sb1 = s2 * swf1;
  float acc = rintf(bf1[tid] / sb1) * sb1;
  const float* wrow = wf1 + tid * 64;
#pragma unroll 8
  for (int k = 0; k < 64; ++k) {
    float q = rintf(wrow[k] / swf1);
    q = fminf(fmaxf(q, -8.f), 7.f);
    acc += xrow[k] * (q * swf1);
  }
  float r = fmaxf(acc, 0.f);
  y3g[b * 128 + tid] = r;
  float m = wave_maxf(r);
  int lane = tid & 63, w = tid >> 6;
  if (!lane) red[w] = m;
  __syncthreads();
  if (!tid) {
    float t = fmaxf(red[0], red[1]);
    atomicMax(&sc->max3, __float_as_uint(t));   // r >= 0: uint order == float order
  }
}

// fc2: 1 block x 320 thr; quantized fc2 + log_softmax.
__global__ void __launch_bounds__(320) k_fc2(
    const float* __restrict__ y3g, const float* __restrict__ wf2,
    const float* __restrict__ bf2, const Scal* __restrict__ sc,
    float* __restrict__ out) {
  __shared__ float zz[320];
  int tid = threadIdx.x;
  float swf2 = mkscale(sc->max_wf2, 7.f);
  float s3 = fmaxf(__uint_as_float(sc->max3), 1e-8f) / 15.f;
  float sb2 = s3 * swf2;
  {
    int b = tid / 10, j = tid - b * 10;
    float acc = rintf(bf2[j] / sb2) * sb2;
    const float* yy = y3g + b * 128;
    const float* wrow = wf2 + j * 128;
#pragma unroll 16
    for (int k = 0; k < 128; ++k) {
      float q = rintf(yy[k] / s3);
      q = fminf(fmaxf(q, 0.f), 15.f);
      float wv = rintf(wrow[k] / swf2);
      wv = fminf(fmaxf(wv, -8.f), 7.f);
      acc += (q * s3) * (wv * swf2);
    }
    zz[tid] = acc;
  }
  __syncthreads();
  if (tid < 32) {
    const float* z = &zz[tid * 10];
    float mm = z[0];
    for (int k = 1; k < 10; ++k) mm = fmaxf(mm, z[k]);
    float ssum = 0.f;
    for (int k = 0; k < 10; ++k) ssum += expf(z[k] - mm);
    float l = mm + logf(ssum);
    for (int k = 0; k < 10; ++k) out[tid * 10 + k] = z[k] - l;
  }
}

extern "C" void kernel_launch(void* const* d_in, const int* in_sizes, int n_in,
                              void* d_out, int out_size, void* d_ws, size_t ws_size,
                              hipStream_t stream) {
  const float* x   = (const float*)d_in[0];
  const float* w1  = (const float*)d_in[1];
  const float* b1  = (const float*)d_in[2];
  const float* w2  = (const float*)d_in[3];
  const float* b2  = (const float*)d_in[4];
  const float* wf1 = (const float*)d_in[5];
  const float* bf1 = (const float*)d_in[6];
  const float* wf2 = (const float*)d_in[7];
  const float* bf2 = (const float*)d_in[8];
  float* out = (float*)d_out;

  char* ws = (char*)d_ws;
  Scal* sc = (Scal*)ws;
  int* pooled_i = (int*)(ws + 1024);            // sc + pooled zeroed by ONE memset
  size_t off = 1024 + 8192;
  unsigned* w2frag = (unsigned*)(ws + off);     off += 4608 * 4;          // MFMA B-frag layout
  float* y3g = (float*)(ws + off);              off += 32 * 128 * 4;      // fc1 output
  off = (off + 255) & ~(size_t)255;
  unsigned char* y1n = (unsigned char*)(ws + off); off += (size_t)NP1 + 256; // planar codes + slack
  (void)ws_size; (void)in_sizes; (void)n_in; (void)out_size;

  hipMemsetAsync(ws, 0, 1024 + 8192, stream);
  k_absmax_xw<<<1028, 256, 0, stream>>>((const float4*)x, NX / 4, w1, w2, wf1, wf2, sc);
  k_conv1a<<<1184 + 11, 448, 0, stream>>>((const float4*)x, w1, b1, w2, sc, w2frag, &sc->max1);
  k_conv1b<<<1184, 448, 0, stream>>>((const float4*)x, w1, b1, sc, y1n);
  k_conv2a<<<C2V_BLK, 256, 0, stream>>>(y1n, w2frag, b2, sc, &sc->max2);
  k_conv2b<<<C2V_BLK, 256, 0, stream>>>(y1n, w2frag, b2, sc, pooled_i);
  k_fc1<<<32, 128, 0, stream>>>(pooled_i, wf1, bf1, sc, y3g);
  k_fc2<<<1, 320, 0, stream>>>(y3g, wf2, bf2, sc, out);
}